// Round 6
// baseline (375.978 us; speedup 1.0000x reference)
//
#include <hip/hip_runtime.h>
#include <hip/hip_bf16.h>
#include <math.h>

typedef short bf16x8 __attribute__((ext_vector_type(8)));
typedef float f32x4 __attribute__((ext_vector_type(4)));
typedef unsigned int u32;

#define B_DIM 8192
#define H_DIM 1024
#define NPATH 256
#define NSTEP 50

__device__ __forceinline__ void gld_lds16(const void* g, void* lds) {
  __builtin_amdgcn_global_load_lds(
      (const __attribute__((address_space(1))) u32*)g,
      (__attribute__((address_space(3))) u32*)lds, 16, 0, 0);
}

__device__ __forceinline__ void cast4(const float* in, __hip_bfloat16* out, int i) {
  float4 v = ((const float4*)in)[i];
  union { __hip_bfloat16 h[4]; short4 s; } u;
  u.h[0] = __float2bfloat16(v.x);
  u.h[1] = __float2bfloat16(v.y);
  u.h[2] = __float2bfloat16(v.z);
  u.h[3] = __float2bfloat16(v.w);
  ((short4*)out)[i] = u.s;
}

// ---------------- fused prep ----------------
// [0,64)          Wc mini-GEMM: wcbt[n][p] = bf16( sum_h W_out[h][n]*W_agg[p][h] )
// [64,68)         v2[d] = sum_h b_agg[h]*W_out[h][d] + b_out[d]
// [68,8260)       cast x -> xb
// [8260,11332)    transpose+cast W_in/W_hid/W_out (1024 32x32 tiles each)
__global__ __launch_bounds__(256) void prep_kernel(
    const float* __restrict__ x, const float* __restrict__ W_in,
    const float* __restrict__ W_hid, const float* __restrict__ W_out,
    const float* __restrict__ W_agg, const float* __restrict__ b_agg,
    const float* __restrict__ b_out,
    __hip_bfloat16* __restrict__ xb, __hip_bfloat16* __restrict__ wtin,
    __hip_bfloat16* __restrict__ wthid, __hip_bfloat16* __restrict__ wtout,
    __hip_bfloat16* __restrict__ wcbt, float* __restrict__ v2) {
  __shared__ float lds[128 * 17];  // Wc: [128][16] W_out tile ; transpose: 32x33
  int bid = blockIdx.x, tid = threadIdx.x;
  if (bid < 64) {
    // block owns n-rows [n0, n0+16), all 256 p (thread = p)
    const int n0 = bid * 16;
    const int p = tid;
    float acc[16];
#pragma unroll
    for (int i = 0; i < 16; ++i) acc[i] = 0.f;
    for (int k0 = 0; k0 < H_DIM; k0 += 128) {
      __syncthreads();  // previous tile consumed
      // load W_out[k0+kk][n0:16] -> lds[kk][i], 512 float4, 2 per thread
#pragma unroll
      for (int q = tid; q < 512; q += 256) {
        int kk = q >> 2, i4 = q & 3;
        float4 v = *(const float4*)(W_out + (size_t)(k0 + kk) * H_DIM + n0 + i4 * 4);
        lds[kk * 17 + i4 * 4 + 0] = v.x;  // pad-17 rows: avoid write conflicts
        lds[kk * 17 + i4 * 4 + 1] = v.y;
        lds[kk * 17 + i4 * 4 + 2] = v.z;
        lds[kk * 17 + i4 * 4 + 3] = v.w;
      }
      __syncthreads();
      const float* warow = W_agg + (size_t)p * H_DIM + k0;
#pragma unroll
      for (int j4 = 0; j4 < 32; ++j4) {
        float4 wa = *(const float4*)(warow + j4 * 4);
        float was[4] = {wa.x, wa.y, wa.z, wa.w};
#pragma unroll
        for (int jj = 0; jj < 4; ++jj) {
          const float* wrow = lds + (j4 * 4 + jj) * 17;
#pragma unroll
          for (int i = 0; i < 16; ++i) acc[i] += was[jj] * wrow[i];  // broadcast read
        }
      }
    }
#pragma unroll
    for (int i = 0; i < 16; ++i)
      wcbt[(size_t)(n0 + i) * NPATH + p] = __float2bfloat16(acc[i]);
    return;
  }
  if (bid < 68) {
    int d = (bid - 64) * 256 + tid;
    float s = 0.f;
#pragma unroll 8
    for (int h = 0; h < H_DIM; ++h) s += b_agg[h] * W_out[(size_t)h * H_DIM + d];
    v2[d] = s + b_out[d];
    return;
  }
  if (bid < 8260) {
    cast4(x, xb, (bid - 68) * 256 + tid);
    return;
  }
  int job = bid - 8260;
  const float* W; __hip_bfloat16* Wt;
  if (job < 1024)      { W = W_in;  Wt = wtin; }
  else if (job < 2048) { W = W_hid; Wt = wthid; job -= 1024; }
  else                 { W = W_out; Wt = wtout; job -= 2048; }
  int tX = job & 31, tY = job >> 5;
  int tx = tid & 31, r4 = tid >> 5;
#pragma unroll
  for (int i = 0; i < 4; ++i) {
    int ty = r4 * 4 + i;
    lds[ty * 33 + tx] = W[(size_t)(tY * 32 + ty) * H_DIM + tX * 32 + tx];
  }
  __syncthreads();
#pragma unroll
  for (int i = 0; i < 4; ++i) {
    int ty = r4 * 4 + i;
    Wt[(size_t)(tX * 32 + ty) * H_DIM + tY * 32 + tx] = __float2bfloat16(lds[tx * 33 + ty]);
  }
}

// ------------- fused feedback + endpoints: per block = 4 batch rows -------------
__global__ __launch_bounds__(256) void fb_end_kernel(
    const __hip_bfloat16* __restrict__ h2b, const float* __restrict__ Wfb,
    const float* __restrict__ bfb, const float* __restrict__ ns,
    __hip_bfloat16* __restrict__ eb, float DI, float SQDT) {
  __shared__ float fv[4];
  int wid = threadIdx.x >> 6, lane = threadIdx.x & 63;
  int row = blockIdx.x * 4 + wid;
  const __hip_bfloat16* hrow = h2b + (size_t)row * H_DIM;
  float s = 0.f;
#pragma unroll
  for (int i = lane; i < H_DIM; i += 64) s += __bfloat162float(hrow[i]) * Wfb[i];
#pragma unroll
  for (int off = 32; off > 0; off >>= 1) s += __shfl_down(s, off);
  if (lane == 0) fv[wid] = 1.0f / (1.0f + expf(-(s + bfb[0])));
  __syncthreads();
#pragma unroll
  for (int w = 0; w < 4; ++w) {
    size_t i = (size_t)(blockIdx.x * 4 + w) * NPATH + threadIdx.x;
    eb[i] = __float2bfloat16(fv[w] * DI + SQDT * ns[i]);
  }
}

// -------- trunk stage: 128x128-tile GEMM (relu->bf16) + co-resident noise ------
// 256 thr, 32KB LDS -> ~4 blocks/CU so GEMM and noise waves share each CU
// (per-CU MFMA-pipe / HBM-pipe overlap, m114). odd bid = GEMM, even = noise.
__global__ __launch_bounds__(256) void stage_kernel(
    const __hip_bfloat16* __restrict__ A, const __hip_bfloat16* __restrict__ Bt,
    const float* __restrict__ bias, __hip_bfloat16* __restrict__ out,
    const float* __restrict__ noise, float* __restrict__ ns,
    int rowStart, int rowCount) {
  __shared__ __hip_bfloat16 As[128 * 64];
  __shared__ __hip_bfloat16 Bs[128 * 64];
  const int bid = blockIdx.x;
  if ((bid & 1) == 0) {
    int j = bid >> 1;  // 512 noise blocks
    for (int r = j * 256 + threadIdx.x; r < rowCount; r += 512 * 256) {
      const float2* p = (const float2*)(noise + (size_t)(rowStart + r) * NSTEP);
      float s = 0.f;
#pragma unroll
      for (int i = 0; i < NSTEP / 2; ++i) { float2 v = p[i]; s += v.x + v.y; }
      ns[rowStart + r] = s;
    }
    return;
  }
  const int gb = bid >> 1;                 // 512 tiles: bm = gb>>3, bn = gb&7
  const int bm = gb >> 3, bn = gb & 7;
  const int tid = threadIdx.x;
  const int lane = tid & 63, wid = tid >> 6;
  const int wr = wid >> 1, wc = wid & 1;
  const int frow = lane & 15, kgrp = lane >> 4;

  f32x4 acc[4][4];
#pragma unroll
  for (int m = 0; m < 4; ++m)
#pragma unroll
    for (int n = 0; n < 4; ++n) acc[m][n] = (f32x4){0.f, 0.f, 0.f, 0.f};

  for (int kt = 0; kt < H_DIM; kt += 64) {
#pragma unroll
    for (int r = 0; r < 4; ++r) {
      int c = r * 256 + tid;
      int row = c >> 3, cc = c & 7;
      gld_lds16((const char*)(A + (size_t)(bm * 128 + row) * H_DIM + kt) + cc * 16,
                (char*)As + c * 16);
      gld_lds16((const char*)(Bt + (size_t)(bn * 128 + row) * H_DIM + kt) + cc * 16,
                (char*)Bs + c * 16);
    }
    __syncthreads();
#pragma unroll
    for (int kk = 0; kk < 64; kk += 32) {
      bf16x8 af[4], bfr[4];
#pragma unroll
      for (int m = 0; m < 4; ++m)
        af[m] = *(const bf16x8*)(As + (wr * 64 + m * 16 + frow) * 64 + kk + kgrp * 8);
#pragma unroll
      for (int n = 0; n < 4; ++n)
        bfr[n] = *(const bf16x8*)(Bs + (wc * 64 + n * 16 + frow) * 64 + kk + kgrp * 8);
#pragma unroll
      for (int m = 0; m < 4; ++m)
#pragma unroll
        for (int n = 0; n < 4; ++n)
          acc[m][n] = __builtin_amdgcn_mfma_f32_16x16x32_bf16(af[m], bfr[n], acc[m][n], 0, 0, 0);
    }
    __syncthreads();
  }

  const int r0 = bm * 128 + wr * 64;
  const int c0 = bn * 128 + wc * 64;
#pragma unroll
  for (int n = 0; n < 4; ++n) {
    int col = c0 + n * 16 + frow;
    float bv = bias[col];
#pragma unroll
    for (int m = 0; m < 4; ++m)
#pragma unroll
      for (int j = 0; j < 4; ++j) {
        int row = r0 + m * 16 + kgrp * 4 + j;
        out[(size_t)row * H_DIM + col] = __float2bfloat16(fmaxf(acc[m][n][j] + bv, 0.f));
      }
  }
}

// ---------------- final: [h2|eb] @ [wtout;wcbt]^T + v2 -> fp32 ----------------
// 256x128 tile, 8 waves, double-buffered counted-vmcnt staging + T2 swizzle
// (pre-swizzled global source + swizzled read, rule #21). Dual K-source:
// kt < 1024 reads (h2b ld 1024, wtout ld 1024); kt >= 1024 reads (eb, wcbt, ld 256).
__global__ __launch_bounds__(512) void final_kernel(
    const __hip_bfloat16* __restrict__ A, const __hip_bfloat16* __restrict__ Bt,
    const __hip_bfloat16* __restrict__ A2, const __hip_bfloat16* __restrict__ Bt2,
    const float* __restrict__ v2, float* __restrict__ out) {
  constexpr int SMHALF = (256 + 128) * 64 * 2;
  __shared__ char smem[2 * SMHALF];
  const int tid = threadIdx.x;
  const int lane = tid & 63, wid = tid >> 6;
  const int wm = wid >> 2, wn = wid & 3;
  const int frow = lane & 15, kgrp = lane >> 4;
  const int bm = blockIdx.x >> 3, bn = blockIdx.x & 7;

  auto stage = [&](int kt, int d) {
    char* dst = smem + d * SMHALF;
    const __hip_bfloat16 *As_, *Bs_;
    int alda, aldb, akt;
    if (kt < H_DIM) { As_ = A; Bs_ = Bt; alda = H_DIM; aldb = H_DIM; akt = kt; }
    else { As_ = A2; Bs_ = Bt2; alda = NPATH; aldb = NPATH; akt = kt - H_DIM; }
#pragma unroll
    for (int j = 0; j < 6; ++j) {
      int c = j * 512 + tid;
      if (j < 4) {
        int row = c >> 3, cb = (c & 7) * 16;
        int col = (cb ^ ((row & 7) << 4)) >> 1;
        gld_lds16((const void*)(As_ + (size_t)(bm * 256 + row) * alda + akt + col), dst + c * 16);
      } else {
        int cB = c - 2048;
        int row = cB >> 3, cb = (cB & 7) * 16;
        int col = (cb ^ ((row & 7) << 4)) >> 1;
        gld_lds16((const void*)(Bs_ + (size_t)(bn * 128 + row) * aldb + akt + col), dst + 32768 + cB * 16);
      }
    }
  };

  f32x4 acc[8][2];
#pragma unroll
  for (int m = 0; m < 8; ++m)
#pragma unroll
    for (int n = 0; n < 2; ++n) acc[m][n] = (f32x4){0.f, 0.f, 0.f, 0.f};

  stage(0, 0);
  const int NT = 1280 >> 6;
  for (int t = 0; t < NT; ++t) {
    const int cur = t & 1;
    if (t + 1 < NT) stage((t + 1) << 6, cur ^ 1);
    if (t == 0 || t + 1 >= NT) {
      asm volatile("s_waitcnt vmcnt(0)" ::: "memory");
    } else {
      asm volatile("s_waitcnt vmcnt(6)" ::: "memory");
    }
    __builtin_amdgcn_s_barrier();

    const char* Ab = smem + cur * SMHALF;
    const char* Bb = Ab + 32768;
    bf16x8 bfr[2][2];
#pragma unroll
    for (int n = 0; n < 2; ++n)
#pragma unroll
      for (int s = 0; s < 2; ++s) {
        int row = wn * 32 + n * 16 + frow;
        int cb = s * 64 + kgrp * 16;
        bfr[n][s] = *(const bf16x8*)(Bb + row * 128 + (cb ^ ((row & 7) << 4)));
      }
#pragma unroll
    for (int mh = 0; mh < 2; ++mh) {
      bf16x8 af[4][2];
#pragma unroll
      for (int m = 0; m < 4; ++m)
#pragma unroll
        for (int s = 0; s < 2; ++s) {
          int row = wm * 128 + (mh * 4 + m) * 16 + frow;
          int cb = s * 64 + kgrp * 16;
          af[m][s] = *(const bf16x8*)(Ab + row * 128 + (cb ^ ((row & 7) << 4)));
        }
#pragma unroll
      for (int m = 0; m < 4; ++m)
#pragma unroll
        for (int n = 0; n < 2; ++n)
#pragma unroll
          for (int s = 0; s < 2; ++s)
            acc[mh * 4 + m][n] = __builtin_amdgcn_mfma_f32_16x16x32_bf16(
                af[m][s], bfr[n][s], acc[mh * 4 + m][n], 0, 0, 0);
    }
    __builtin_amdgcn_s_barrier();
  }

  const int r0 = bm * 256 + wm * 128;
  const int c0 = bn * 128 + wn * 32;
#pragma unroll
  for (int n = 0; n < 2; ++n) {
    int col = c0 + n * 16 + frow;
    float bv = v2[col];
#pragma unroll
    for (int m = 0; m < 8; ++m)
#pragma unroll
      for (int j = 0; j < 4; ++j) {
        int row = r0 + m * 16 + kgrp * 4 + j;
        out[(size_t)row * H_DIM + col] = acc[m][n][j] + bv;
      }
  }
}

extern "C" void kernel_launch(void* const* d_in, const int* in_sizes, int n_in,
                              void* d_out, int out_size, void* d_ws, size_t ws_size,
                              hipStream_t stream) {
  (void)in_sizes; (void)n_in; (void)out_size; (void)ws_size;
  const float* x     = (const float*)d_in[0];
  const float* W_in  = (const float*)d_in[1];
  const float* b_in  = (const float*)d_in[2];
  const float* W_hid = (const float*)d_in[3];
  const float* b_hid = (const float*)d_in[4];
  const float* W_fb  = (const float*)d_in[5];
  const float* b_fb  = (const float*)d_in[6];
  const float* W_agg = (const float*)d_in[7];
  const float* b_agg = (const float*)d_in[8];
  const float* W_out = (const float*)d_in[9];
  const float* b_out = (const float*)d_in[10];
  const float* noise = (const float*)d_in[11];

  const int B = B_DIM, H = H_DIM, P = NPATH;
  const int R = B * P;

  size_t off = 0;
  char* base = (char*)d_ws;
  auto take = [&](size_t bytes) -> char* {
    char* r = base + off;
    off = (off + bytes + 255) & ~(size_t)255;
    return r;
  };
  __hip_bfloat16* xb    = (__hip_bfloat16*)take((size_t)B * H * 2);
  __hip_bfloat16* h1b   = (__hip_bfloat16*)take((size_t)B * H * 2);
  __hip_bfloat16* h2b   = (__hip_bfloat16*)take((size_t)B * H * 2);
  __hip_bfloat16* wtin  = (__hip_bfloat16*)take((size_t)H * H * 2);
  __hip_bfloat16* wthid = (__hip_bfloat16*)take((size_t)H * H * 2);
  __hip_bfloat16* wtout = (__hip_bfloat16*)take((size_t)H * H * 2);
  __hip_bfloat16* wcbt  = (__hip_bfloat16*)take((size_t)H * P * 2);
  float* v2 = (float*)take((size_t)H * 4);
  float* ns = (float*)take((size_t)R * 4);
  __hip_bfloat16* eb = (__hip_bfloat16*)take((size_t)R * 2);

  float dt = 1.0f / NSTEP;
  float DI = 0.f;
  for (int j = 0; j < NSTEP; ++j) DI += expf(-0.1f * ((float)j * dt));
  DI *= dt;
  float SQDT = sqrtf(dt);

  prep_kernel<<<11332, 256, 0, stream>>>(x, W_in, W_hid, W_out, W_agg, b_agg, b_out,
                                         xb, wtin, wthid, wtout, wcbt, v2);
  // trunk stages: 512 GEMM tiles + 512 noise blocks, all co-resident (4 blk/CU)
  stage_kernel<<<1024, 256, 0, stream>>>(xb, wtin, b_in, h1b, noise, ns, 0, R / 2);
  stage_kernel<<<1024, 256, 0, stream>>>(h1b, wthid, b_hid, h2b, noise, ns, R / 2, R - R / 2);
  fb_end_kernel<<<B / 4, 256, 0, stream>>>(h2b, W_fb, b_fb, ns, eb, DI, SQDT);
  // final: [h2|eb] @ [wtout;wcbt]^T + v2 -> fp32, K=1280 dual-source
  final_kernel<<<256, 512, 0, stream>>>(h2b, wtout, eb, wcbt, v2, (float*)d_out);
}

// Round 7
// 254.741 us; speedup vs baseline: 1.4759x; 1.4759x over previous
//
#include <hip/hip_runtime.h>
#include <hip/hip_bf16.h>
#include <math.h>

typedef short bf16x8 __attribute__((ext_vector_type(8)));
typedef float f32x4 __attribute__((ext_vector_type(4)));
typedef unsigned int u32;

#define B_DIM 8192
#define H_DIM 1024
#define NPATH 256
#define NSTEP 50

__device__ __forceinline__ void gld_lds16(const void* g, void* lds) {
  __builtin_amdgcn_global_load_lds(
      (const __attribute__((address_space(1))) u32*)g,
      (__attribute__((address_space(3))) u32*)lds, 16, 0, 0);
}

__device__ __forceinline__ void cast4(const float* in, __hip_bfloat16* out, int i) {
  float4 v = ((const float4*)in)[i];
  union { __hip_bfloat16 h[4]; short4 s; } u;
  u.h[0] = __float2bfloat16(v.x);
  u.h[1] = __float2bfloat16(v.y);
  u.h[2] = __float2bfloat16(v.z);
  u.h[3] = __float2bfloat16(v.w);
  ((short4*)out)[i] = u.s;
}

// ---------------- fused prep (pure data movement, no compute stragglers) -------
// [0,8192)        cast x -> xb
// [8192,11264)    transpose+cast W_in/W_hid/W_out (1024 32x32 tiles each)
// [11264,11520)   plain cast W_agg -> waggb
// [11520,11524)   v2[d] = sum_h b_agg[h]*W_out[h][d] + b_out[d]  (coalesced)
__global__ __launch_bounds__(256) void prep_kernel(
    const float* __restrict__ x, const float* __restrict__ W_in,
    const float* __restrict__ W_hid, const float* __restrict__ W_out,
    const float* __restrict__ W_agg, const float* __restrict__ b_agg,
    const float* __restrict__ b_out,
    __hip_bfloat16* __restrict__ xb, __hip_bfloat16* __restrict__ wtin,
    __hip_bfloat16* __restrict__ wthid, __hip_bfloat16* __restrict__ wtout,
    __hip_bfloat16* __restrict__ waggb, float* __restrict__ v2) {
  __shared__ float t[32][33];
  int bid = blockIdx.x, tid = threadIdx.x;
  if (bid < 8192) {
    cast4(x, xb, bid * 256 + tid);
    return;
  }
  if (bid < 11264) {
    int job = bid - 8192;
    const float* W; __hip_bfloat16* Wt;
    if (job < 1024)      { W = W_in;  Wt = wtin; }
    else if (job < 2048) { W = W_hid; Wt = wthid; job -= 1024; }
    else                 { W = W_out; Wt = wtout; job -= 2048; }
    int tX = job & 31, tY = job >> 5;
    int tx = tid & 31, r4 = tid >> 5;
#pragma unroll
    for (int i = 0; i < 4; ++i) {
      int ty = r4 * 4 + i;
      t[ty][tx] = W[(size_t)(tY * 32 + ty) * H_DIM + tX * 32 + tx];
    }
    __syncthreads();
#pragma unroll
    for (int i = 0; i < 4; ++i) {
      int ty = r4 * 4 + i;
      Wt[(size_t)(tX * 32 + ty) * H_DIM + tY * 32 + tx] = __float2bfloat16(t[tx][ty]);
    }
    return;
  }
  if (bid < 11520) {
    cast4(W_agg, waggb, (bid - 11264) * 256 + tid);
    return;
  }
  int d = (bid - 11520) * 256 + tid;
  float s = 0.f;
#pragma unroll 8
  for (int h = 0; h < H_DIM; ++h) s += b_agg[h] * W_out[(size_t)h * H_DIM + d];
  v2[d] = s + b_out[d];
}

// ------------- fused feedback + endpoints: per block = 4 batch rows -------------
__global__ __launch_bounds__(256) void fb_end_kernel(
    const __hip_bfloat16* __restrict__ h2b, const float* __restrict__ Wfb,
    const float* __restrict__ bfb, const float* __restrict__ ns,
    __hip_bfloat16* __restrict__ eb, float DI, float SQDT) {
  __shared__ float fv[4];
  int wid = threadIdx.x >> 6, lane = threadIdx.x & 63;
  int row = blockIdx.x * 4 + wid;
  const __hip_bfloat16* hrow = h2b + (size_t)row * H_DIM;
  float s = 0.f;
#pragma unroll
  for (int i = lane; i < H_DIM; i += 64) s += __bfloat162float(hrow[i]) * Wfb[i];
#pragma unroll
  for (int off = 32; off > 0; off >>= 1) s += __shfl_down(s, off);
  if (lane == 0) fv[wid] = 1.0f / (1.0f + expf(-(s + bfb[0])));
  __syncthreads();
#pragma unroll
  for (int w = 0; w < 4; ++w) {
    size_t i = (size_t)(blockIdx.x * 4 + w) * NPATH + threadIdx.x;
    eb[i] = __float2bfloat16(fv[w] * DI + SQDT * ns[i]);
  }
}

// -------- trunk stage: 128x128-tile GEMM (relu->bf16) + co-resident noise ------
// 256 thr, 32KB LDS -> multiple blocks/CU so GEMM and noise waves share each CU.
// bid < 1024: odd = trunk GEMM tile, even = noise reduction chunk.
// bid >= 1024 (stage1 only, 16 blocks): Wc tile  wcbt = wtout @ waggb^T (K=1024,
// M=1024, N=256) using the identical K-loop — rides the same grid, ~3% extra work.
__global__ __launch_bounds__(256) void stage_kernel(
    const __hip_bfloat16* __restrict__ A, const __hip_bfloat16* __restrict__ Bt,
    const float* __restrict__ bias, __hip_bfloat16* __restrict__ out,
    const float* __restrict__ noise, float* __restrict__ ns,
    int rowStart, int rowCount,
    const __hip_bfloat16* __restrict__ wcA, const __hip_bfloat16* __restrict__ wcBt,
    __hip_bfloat16* __restrict__ wcOut) {
  __shared__ __hip_bfloat16 As[128 * 64];
  __shared__ __hip_bfloat16 Bs[128 * 64];
  const int bid = blockIdx.x;
  if (bid < 1024 && (bid & 1) == 0) {
    int j = bid >> 1;  // 512 noise blocks
    for (int r = j * 256 + threadIdx.x; r < rowCount; r += 512 * 256) {
      const float2* p = (const float2*)(noise + (size_t)(rowStart + r) * NSTEP);
      float s = 0.f;
#pragma unroll
      for (int i = 0; i < NSTEP / 2; ++i) { float2 v = p[i]; s += v.x + v.y; }
      ns[rowStart + r] = s;
    }
    return;
  }
  // role decode (wave-uniform)
  const __hip_bfloat16 *Ap, *Btp; __hip_bfloat16* outp;
  const float* biasp; int bm, bn, N; bool relu;
  if (bid < 1024) {
    int gb = bid >> 1;  // 512 tiles: bm = gb>>3, bn = gb&7
    bm = gb >> 3; bn = gb & 7; Ap = A; Btp = Bt; outp = out; biasp = bias;
    N = H_DIM; relu = true;
  } else {
    int g = bid - 1024;  // 16 tiles: M=1024 (8) x N=256 (2)
    bm = g >> 1; bn = g & 1; Ap = wcA; Btp = wcBt; outp = wcOut; biasp = nullptr;
    N = NPATH; relu = false;
  }
  const int tid = threadIdx.x;
  const int lane = tid & 63, wid = tid >> 6;
  const int wr = wid >> 1, wc = wid & 1;
  const int frow = lane & 15, kgrp = lane >> 4;

  f32x4 acc[4][4];
#pragma unroll
  for (int m = 0; m < 4; ++m)
#pragma unroll
    for (int n = 0; n < 4; ++n) acc[m][n] = (f32x4){0.f, 0.f, 0.f, 0.f};

  for (int kt = 0; kt < H_DIM; kt += 64) {
#pragma unroll
    for (int r = 0; r < 4; ++r) {
      int c = r * 256 + tid;
      int row = c >> 3, cc = c & 7;
      gld_lds16((const char*)(Ap + (size_t)(bm * 128 + row) * H_DIM + kt) + cc * 16,
                (char*)As + c * 16);
      gld_lds16((const char*)(Btp + (size_t)(bn * 128 + row) * H_DIM + kt) + cc * 16,
                (char*)Bs + c * 16);
    }
    __syncthreads();
#pragma unroll
    for (int kk = 0; kk < 64; kk += 32) {
      bf16x8 af[4], bfr[4];
#pragma unroll
      for (int m = 0; m < 4; ++m)
        af[m] = *(const bf16x8*)(As + (wr * 64 + m * 16 + frow) * 64 + kk + kgrp * 8);
#pragma unroll
      for (int n = 0; n < 4; ++n)
        bfr[n] = *(const bf16x8*)(Bs + (wc * 64 + n * 16 + frow) * 64 + kk + kgrp * 8);
#pragma unroll
      for (int m = 0; m < 4; ++m)
#pragma unroll
        for (int n = 0; n < 4; ++n)
          acc[m][n] = __builtin_amdgcn_mfma_f32_16x16x32_bf16(af[m], bfr[n], acc[m][n], 0, 0, 0);
    }
    __syncthreads();
  }

  const int r0 = bm * 128 + wr * 64;
  const int c0 = bn * 128 + wc * 64;
#pragma unroll
  for (int n = 0; n < 4; ++n) {
    int col = c0 + n * 16 + frow;
    float bv = biasp ? biasp[col] : 0.f;
#pragma unroll
    for (int m = 0; m < 4; ++m)
#pragma unroll
      for (int j = 0; j < 4; ++j) {
        int row = r0 + m * 16 + kgrp * 4 + j;
        float v = acc[m][n][j] + bv;
        if (relu) v = fmaxf(v, 0.f);
        outp[(size_t)row * N + col] = __float2bfloat16(v);
      }
  }
}

// ---------------- final: [h2|eb] @ [wtout;wcbt]^T + v2 -> fp32 ----------------
// 256x128 tile, 8 waves, double-buffered counted-vmcnt staging + T2 swizzle
// (pre-swizzled global source + swizzled read, rule #21). Dual K-source:
// kt < 1024 reads (h2b, wtout, ld 1024); kt >= 1024 reads (eb, wcbt, ld 256).
__global__ __launch_bounds__(512) void final_kernel(
    const __hip_bfloat16* __restrict__ A, const __hip_bfloat16* __restrict__ Bt,
    const __hip_bfloat16* __restrict__ A2, const __hip_bfloat16* __restrict__ Bt2,
    const float* __restrict__ v2, float* __restrict__ out) {
  constexpr int SMHALF = (256 + 128) * 64 * 2;
  __shared__ char smem[2 * SMHALF];
  const int tid = threadIdx.x;
  const int lane = tid & 63, wid = tid >> 6;
  const int wm = wid >> 2, wn = wid & 3;
  const int frow = lane & 15, kgrp = lane >> 4;
  const int bm = blockIdx.x >> 3, bn = blockIdx.x & 7;

  auto stage = [&](int kt, int d) {
    char* dst = smem + d * SMHALF;
    const __hip_bfloat16 *As_, *Bs_;
    int alda, aldb, akt;
    if (kt < H_DIM) { As_ = A; Bs_ = Bt; alda = H_DIM; aldb = H_DIM; akt = kt; }
    else { As_ = A2; Bs_ = Bt2; alda = NPATH; aldb = NPATH; akt = kt - H_DIM; }
#pragma unroll
    for (int j = 0; j < 6; ++j) {
      int c = j * 512 + tid;
      if (j < 4) {
        int row = c >> 3, cb = (c & 7) * 16;
        int col = (cb ^ ((row & 7) << 4)) >> 1;
        gld_lds16((const void*)(As_ + (size_t)(bm * 256 + row) * alda + akt + col), dst + c * 16);
      } else {
        int cB = c - 2048;
        int row = cB >> 3, cb = (cB & 7) * 16;
        int col = (cb ^ ((row & 7) << 4)) >> 1;
        gld_lds16((const void*)(Bs_ + (size_t)(bn * 128 + row) * aldb + akt + col), dst + 32768 + cB * 16);
      }
    }
  };

  f32x4 acc[8][2];
#pragma unroll
  for (int m = 0; m < 8; ++m)
#pragma unroll
    for (int n = 0; n < 2; ++n) acc[m][n] = (f32x4){0.f, 0.f, 0.f, 0.f};

  stage(0, 0);
  const int NT = 1280 >> 6;
  for (int t = 0; t < NT; ++t) {
    const int cur = t & 1;
    if (t + 1 < NT) stage((t + 1) << 6, cur ^ 1);
    if (t == 0 || t + 1 >= NT) {
      asm volatile("s_waitcnt vmcnt(0)" ::: "memory");
    } else {
      asm volatile("s_waitcnt vmcnt(6)" ::: "memory");
    }
    __builtin_amdgcn_s_barrier();

    const char* Ab = smem + cur * SMHALF;
    const char* Bb = Ab + 32768;
    bf16x8 bfr[2][2];
#pragma unroll
    for (int n = 0; n < 2; ++n)
#pragma unroll
      for (int s = 0; s < 2; ++s) {
        int row = wn * 32 + n * 16 + frow;
        int cb = s * 64 + kgrp * 16;
        bfr[n][s] = *(const bf16x8*)(Bb + row * 128 + (cb ^ ((row & 7) << 4)));
      }
#pragma unroll
    for (int mh = 0; mh < 2; ++mh) {
      bf16x8 af[4][2];
#pragma unroll
      for (int m = 0; m < 4; ++m)
#pragma unroll
        for (int s = 0; s < 2; ++s) {
          int row = wm * 128 + (mh * 4 + m) * 16 + frow;
          int cb = s * 64 + kgrp * 16;
          af[m][s] = *(const bf16x8*)(Ab + row * 128 + (cb ^ ((row & 7) << 4)));
        }
#pragma unroll
      for (int m = 0; m < 4; ++m)
#pragma unroll
        for (int n = 0; n < 2; ++n)
#pragma unroll
          for (int s = 0; s < 2; ++s)
            acc[mh * 4 + m][n] = __builtin_amdgcn_mfma_f32_16x16x32_bf16(
                af[m][s], bfr[n][s], acc[mh * 4 + m][n], 0, 0, 0);
    }
    __builtin_amdgcn_s_barrier();
  }

  const int r0 = bm * 256 + wm * 128;
  const int c0 = bn * 128 + wn * 32;
#pragma unroll
  for (int n = 0; n < 2; ++n) {
    int col = c0 + n * 16 + frow;
    float bv = v2[col];
#pragma unroll
    for (int m = 0; m < 8; ++m)
#pragma unroll
      for (int j = 0; j < 4; ++j) {
        int row = r0 + m * 16 + kgrp * 4 + j;
        out[(size_t)row * H_DIM + col] = acc[m][n][j] + bv;
      }
  }
}

extern "C" void kernel_launch(void* const* d_in, const int* in_sizes, int n_in,
                              void* d_out, int out_size, void* d_ws, size_t ws_size,
                              hipStream_t stream) {
  (void)in_sizes; (void)n_in; (void)out_size; (void)ws_size;
  const float* x     = (const float*)d_in[0];
  const float* W_in  = (const float*)d_in[1];
  const float* b_in  = (const float*)d_in[2];
  const float* W_hid = (const float*)d_in[3];
  const float* b_hid = (const float*)d_in[4];
  const float* W_fb  = (const float*)d_in[5];
  const float* b_fb  = (const float*)d_in[6];
  const float* W_agg = (const float*)d_in[7];
  const float* b_agg = (const float*)d_in[8];
  const float* W_out = (const float*)d_in[9];
  const float* b_out = (const float*)d_in[10];
  const float* noise = (const float*)d_in[11];

  const int B = B_DIM, H = H_DIM, P = NPATH;
  const int R = B * P;

  size_t off = 0;
  char* base = (char*)d_ws;
  auto take = [&](size_t bytes) -> char* {
    char* r = base + off;
    off = (off + bytes + 255) & ~(size_t)255;
    return r;
  };
  __hip_bfloat16* xb    = (__hip_bfloat16*)take((size_t)B * H * 2);
  __hip_bfloat16* h1b   = (__hip_bfloat16*)take((size_t)B * H * 2);
  __hip_bfloat16* h2b   = (__hip_bfloat16*)take((size_t)B * H * 2);
  __hip_bfloat16* wtin  = (__hip_bfloat16*)take((size_t)H * H * 2);
  __hip_bfloat16* wthid = (__hip_bfloat16*)take((size_t)H * H * 2);
  __hip_bfloat16* wtout = (__hip_bfloat16*)take((size_t)H * H * 2);
  __hip_bfloat16* waggb = (__hip_bfloat16*)take((size_t)P * H * 2);
  __hip_bfloat16* wcbt  = (__hip_bfloat16*)take((size_t)H * P * 2);
  float* v2 = (float*)take((size_t)H * 4);
  float* ns = (float*)take((size_t)R * 4);
  __hip_bfloat16* eb = (__hip_bfloat16*)take((size_t)R * 2);

  float dt = 1.0f / NSTEP;
  float DI = 0.f;
  for (int j = 0; j < NSTEP; ++j) DI += expf(-0.1f * ((float)j * dt));
  DI *= dt;
  float SQDT = sqrtf(dt);

  prep_kernel<<<11524, 256, 0, stream>>>(x, W_in, W_hid, W_out, W_agg, b_agg, b_out,
                                         xb, wtin, wthid, wtout, waggb, v2);
  // stage1: 512 trunk tiles + 512 noise blocks + 16 Wc tiles (wcbt = wtout@waggb^T)
  stage_kernel<<<1040, 256, 0, stream>>>(xb, wtin, b_in, h1b, noise, ns, 0, R / 2,
                                         wtout, waggb, wcbt);
  // stage2: 512 trunk tiles + 512 noise blocks
  stage_kernel<<<1024, 256, 0, stream>>>(h1b, wthid, b_hid, h2b, noise, ns, R / 2, R - R / 2,
                                         nullptr, nullptr, nullptr);
  fb_end_kernel<<<B / 4, 256, 0, stream>>>(h2b, W_fb, b_fb, ns, eb, DI, SQDT);
  // final: [h2|eb] @ [wtout;wcbt]^T + v2 -> fp32, K=1280 dual-source
  final_kernel<<<256, 512, 0, stream>>>(h2b, wtout, eb, wcbt, v2, (float*)d_out);
}

// Round 8
// 193.241 us; speedup vs baseline: 1.9456x; 1.3183x over previous
//
#include <hip/hip_runtime.h>
#include <hip/hip_bf16.h>
#include <math.h>

typedef short bf16x8 __attribute__((ext_vector_type(8)));
typedef float f32x4 __attribute__((ext_vector_type(4)));
typedef unsigned int u32;

#define B_DIM 8192
#define H_DIM 1024
#define NPATH 256
#define NSTEP 50

__device__ __forceinline__ void gld_lds16(const void* g, void* lds) {
  __builtin_amdgcn_global_load_lds(
      (const __attribute__((address_space(1))) u32*)g,
      (__attribute__((address_space(3))) u32*)lds, 16, 0, 0);
}

__device__ __forceinline__ void cast4(const float* in, __hip_bfloat16* out, int i) {
  float4 v = ((const float4*)in)[i];
  union { __hip_bfloat16 h[4]; short4 s; } u;
  u.h[0] = __float2bfloat16(v.x);
  u.h[1] = __float2bfloat16(v.y);
  u.h[2] = __float2bfloat16(v.z);
  u.h[3] = __float2bfloat16(v.w);
  ((short4*)out)[i] = u.s;
}

// ---------------- fused prep: pure data movement, no low-parallelism jobs ------
// [0,8192)        cast x -> xb
// [8192,11264)    transpose+cast W_in/W_hid/W_out (1024 32x32 tiles each)
// [11264,11520)   transpose+cast W_agg -> wtagg[1024][256] (256 tiles)
__global__ __launch_bounds__(256) void prep_kernel(
    const float* __restrict__ x, const float* __restrict__ W_in,
    const float* __restrict__ W_hid, const float* __restrict__ W_out,
    const float* __restrict__ W_agg,
    __hip_bfloat16* __restrict__ xb, __hip_bfloat16* __restrict__ wtin,
    __hip_bfloat16* __restrict__ wthid, __hip_bfloat16* __restrict__ wtout,
    __hip_bfloat16* __restrict__ wtagg) {
  __shared__ float t[32][33];
  int bid = blockIdx.x, tid = threadIdx.x;
  if (bid < 8192) {
    cast4(x, xb, bid * 256 + tid);
    return;
  }
  int job = bid - 8192;
  const float* W; __hip_bfloat16* Wt; int R, C;
  if (job < 1024)      { W = W_in;  Wt = wtin;  R = 1024; C = 1024; }
  else if (job < 2048) { W = W_hid; Wt = wthid; R = 1024; C = 1024; job -= 1024; }
  else if (job < 3072) { W = W_out; Wt = wtout; R = 1024; C = 1024; job -= 2048; }
  else                 { W = W_agg; Wt = wtagg; R = 256;  C = 1024; job -= 3072; }
  int nTx = C / 32;
  int tX = job % nTx, tY = job / nTx;
  int tx = tid & 31, r4 = tid >> 5;
#pragma unroll
  for (int i = 0; i < 4; ++i) {
    int ty = r4 * 4 + i;
    t[ty][tx] = W[(size_t)(tY * 32 + ty) * C + tX * 32 + tx];
  }
  __syncthreads();
#pragma unroll
  for (int i = 0; i < 4; ++i) {
    int ty = r4 * 4 + i;
    Wt[(size_t)(tX * 32 + ty) * R + tY * 32 + tx] = __float2bfloat16(t[tx][ty]);
  }
}

// ------------- fused feedback + endpoints: per block = 4 batch rows -------------
__global__ __launch_bounds__(256) void fb_end_kernel(
    const __hip_bfloat16* __restrict__ h2b, const float* __restrict__ Wfb,
    const float* __restrict__ bfb, const float* __restrict__ ns,
    __hip_bfloat16* __restrict__ eb, float DI, float SQDT) {
  __shared__ float fv[4];
  int wid = threadIdx.x >> 6, lane = threadIdx.x & 63;
  int row = blockIdx.x * 4 + wid;
  const __hip_bfloat16* hrow = h2b + (size_t)row * H_DIM;
  float s = 0.f;
#pragma unroll
  for (int i = lane; i < H_DIM; i += 64) s += __bfloat162float(hrow[i]) * Wfb[i];
#pragma unroll
  for (int off = 32; off > 0; off >>= 1) s += __shfl_down(s, off);
  if (lane == 0) fv[wid] = 1.0f / (1.0f + expf(-(s + bfb[0])));
  __syncthreads();
#pragma unroll
  for (int w = 0; w < 4; ++w) {
    size_t i = (size_t)(blockIdx.x * 4 + w) * NPATH + threadIdx.x;
    eb[i] = __float2bfloat16(fv[w] * DI + SQDT * ns[i]);
  }
}

// ---------------- pipelined 256-row-tile MFMA GEMM core (round-4 proven) -------
// BM=256, BN=TBN, BK=64, 8 waves (2Mx4N). Counted-vmcnt double-buffered staging
// + LDS XOR swizzle via pre-swizzled global source (rule #21 pairing).
// XCD-aware bijective tile remap: tile = (bid&7)*(nGemm/8) + (bid>>3) so each
// XCD's L2 holds 4 contiguous A-panels + the B panel (T1).
// MODE 0: relu(acc+bias)->bf16 ; MODE 2: acc+bias+extra->bf16 ; MODE 3: fp32.
// NOISE: blocks >= nGemm do the noise row-reduction (contiguous role split).
template <int TBN, int MODE, bool NOISE>
__global__ __launch_bounds__(512) void gemm8(
    const __hip_bfloat16* __restrict__ A, const __hip_bfloat16* __restrict__ Bt,
    const float* __restrict__ bias, const __hip_bfloat16* __restrict__ extra,
    void* __restrict__ out, int N, int K, int nGemm,
    const float* __restrict__ noise, float* __restrict__ ns,
    int rowStart, int rowCount) {
  constexpr int NR = TBN / 64;                 // per-wave n-fragments: 4 or 2
  constexpr int SMHALF = (256 + TBN) * 64 * 2; // bytes per double-buffer half
  constexpr int NLOADS = (256 + TBN) / 64;     // gld_lds16 per thread per stage
  __shared__ char smem[2 * SMHALF];

  if (NOISE && blockIdx.x >= nGemm) {
    int j = blockIdx.x - nGemm;
    int stride = (gridDim.x - nGemm) * 512;
    for (int r = j * 512 + threadIdx.x; r < rowCount; r += stride) {
      const float2* p = (const float2*)(noise + (size_t)(rowStart + r) * NSTEP);
      float s = 0.f;
#pragma unroll
      for (int i = 0; i < NSTEP / 2; ++i) { float2 v = p[i]; s += v.x + v.y; }
      ns[rowStart + r] = s;
    }
    return;
  }

  const int tid = threadIdx.x;
  const int lane = tid & 63, wid = tid >> 6;
  const int wm = wid >> 2, wn = wid & 3;
  const int frow = lane & 15, kgrp = lane >> 4;
  // XCD-aware bijective remap (nGemm % 8 == 0 always here)
  const int cpx = nGemm >> 3;
  const int gb = (blockIdx.x & 7) * cpx + (blockIdx.x >> 3);
  const int gx = N / TBN;
  const int bm = gb / gx, bn = gb % gx;
  const size_t arow0 = (size_t)(bm * 256) * K;
  const size_t brow0 = (size_t)(bn * TBN) * K;

  auto stage = [&](int kt, int d) {
    char* dst = smem + d * SMHALF;
#pragma unroll
    for (int j = 0; j < NLOADS; ++j) {
      int c = j * 512 + tid;
      if (j < 4) {  // A tile: 256x64 = 2048 16B-chunks
        int row = c >> 3, cb = (c & 7) * 16;
        int col = (cb ^ ((row & 7) << 4)) >> 1;  // pre-swizzled source column
        gld_lds16((const void*)(A + arow0 + (size_t)row * K + kt + col), dst + c * 16);
      } else {      // B tile: TBN x 64
        int cB = c - 2048;
        int row = cB >> 3, cb = (cB & 7) * 16;
        int col = (cb ^ ((row & 7) << 4)) >> 1;
        gld_lds16((const void*)(Bt + brow0 + (size_t)row * K + kt + col), dst + 32768 + cB * 16);
      }
    }
  };

  f32x4 acc[8][NR];
#pragma unroll
  for (int m = 0; m < 8; ++m)
#pragma unroll
    for (int n = 0; n < NR; ++n) acc[m][n] = (f32x4){0.f, 0.f, 0.f, 0.f};

  stage(0, 0);
  const int NT = K >> 6;
  for (int t = 0; t < NT; ++t) {
    const int cur = t & 1;
    if (t + 1 < NT) stage((t + 1) << 6, cur ^ 1);
    if (t == 0 || t + 1 >= NT) {
      asm volatile("s_waitcnt vmcnt(0)" ::: "memory");
    } else if constexpr (TBN == 256) {
      asm volatile("s_waitcnt vmcnt(8)" ::: "memory");
    } else {
      asm volatile("s_waitcnt vmcnt(6)" ::: "memory");
    }
    __builtin_amdgcn_s_barrier();

    const char* Ab = smem + cur * SMHALF;
    const char* Bb = Ab + 32768;
    bf16x8 bfr[NR][2];
#pragma unroll
    for (int n = 0; n < NR; ++n)
#pragma unroll
      for (int s = 0; s < 2; ++s) {
        int row = wn * (NR * 16) + n * 16 + frow;
        int cb = s * 64 + kgrp * 16;
        bfr[n][s] = *(const bf16x8*)(Bb + row * 128 + (cb ^ ((row & 7) << 4)));
      }
#pragma unroll
    for (int mh = 0; mh < 2; ++mh) {
      bf16x8 af[4][2];
#pragma unroll
      for (int m = 0; m < 4; ++m)
#pragma unroll
        for (int s = 0; s < 2; ++s) {
          int row = wm * 128 + (mh * 4 + m) * 16 + frow;
          int cb = s * 64 + kgrp * 16;
          af[m][s] = *(const bf16x8*)(Ab + row * 128 + (cb ^ ((row & 7) << 4)));
        }
#pragma unroll
      for (int m = 0; m < 4; ++m)
#pragma unroll
        for (int n = 0; n < NR; ++n)
#pragma unroll
          for (int s = 0; s < 2; ++s)
            acc[mh * 4 + m][n] = __builtin_amdgcn_mfma_f32_16x16x32_bf16(
                af[m][s], bfr[n][s], acc[mh * 4 + m][n], 0, 0, 0);
    }
    __builtin_amdgcn_s_barrier();  // all waves done reading buf[cur] before overwrite
  }

  // epilogue: C/D layout col = lane&15, row = (lane>>4)*4 + j  [verified mapping]
  const int r0 = bm * 256 + wm * 128;
  const int c0 = bn * TBN + wn * (NR * 16);
#pragma unroll
  for (int n = 0; n < NR; ++n) {
    int col = c0 + n * 16 + frow;
    float bv = bias[col];
#pragma unroll
    for (int m = 0; m < 8; ++m)
#pragma unroll
      for (int j = 0; j < 4; ++j) {
        int row = r0 + m * 16 + kgrp * 4 + j;
        float v = acc[m][n][j] + bv;
        if (MODE == 0) {
          v = fmaxf(v, 0.f);
          ((__hip_bfloat16*)out)[(size_t)row * N + col] = __float2bfloat16(v);
        } else if (MODE == 2) {
          v += __bfloat162float(extra[(size_t)row * N + col]);
          ((__hip_bfloat16*)out)[(size_t)row * N + col] = __float2bfloat16(v);
        } else {
          ((float*)out)[(size_t)row * N + col] = v;
        }
      }
  }
}

extern "C" void kernel_launch(void* const* d_in, const int* in_sizes, int n_in,
                              void* d_out, int out_size, void* d_ws, size_t ws_size,
                              hipStream_t stream) {
  (void)in_sizes; (void)n_in; (void)out_size; (void)ws_size;
  const float* x     = (const float*)d_in[0];
  const float* W_in  = (const float*)d_in[1];
  const float* b_in  = (const float*)d_in[2];
  const float* W_hid = (const float*)d_in[3];
  const float* b_hid = (const float*)d_in[4];
  const float* W_fb  = (const float*)d_in[5];
  const float* b_fb  = (const float*)d_in[6];
  const float* W_agg = (const float*)d_in[7];
  const float* b_agg = (const float*)d_in[8];
  const float* W_out = (const float*)d_in[9];
  const float* b_out = (const float*)d_in[10];
  const float* noise = (const float*)d_in[11];

  const int B = B_DIM, H = H_DIM, P = NPATH;
  const int R = B * P;

  size_t off = 0;
  char* base = (char*)d_ws;
  auto take = [&](size_t bytes) -> char* {
    char* r = base + off;
    off = (off + bytes + 255) & ~(size_t)255;
    return r;
  };
  __hip_bfloat16* xb    = (__hip_bfloat16*)take((size_t)B * H * 2);  // reused as `combined`
  __hip_bfloat16* h1b   = (__hip_bfloat16*)take((size_t)B * H * 2);
  __hip_bfloat16* h2b   = (__hip_bfloat16*)take((size_t)B * H * 2);
  __hip_bfloat16* wtin  = (__hip_bfloat16*)take((size_t)H * H * 2);
  __hip_bfloat16* wthid = (__hip_bfloat16*)take((size_t)H * H * 2);
  __hip_bfloat16* wtout = (__hip_bfloat16*)take((size_t)H * H * 2);
  __hip_bfloat16* wtagg = (__hip_bfloat16*)take((size_t)H * P * 2);
  float* ns = (float*)take((size_t)R * 4);
  __hip_bfloat16* eb = (__hip_bfloat16*)take((size_t)R * 2);

  float dt = 1.0f / NSTEP;
  float DI = 0.f;
  for (int j = 0; j < NSTEP; ++j) DI += expf(-0.1f * ((float)j * dt));
  DI *= dt;
  float SQDT = sqrtf(dt);

  prep_kernel<<<11520, 256, 0, stream>>>(x, W_in, W_hid, W_out, W_agg,
                                         xb, wtin, wthid, wtout, wtagg);

  // trunk stages: 128 GEMM tiles (256x256) + 256 noise blocks, contiguous split
  gemm8<256, 0, true><<<384, 512, 0, stream>>>(xb, wtin, b_in, nullptr, h1b,
                                               H, H, 128, noise, ns, 0, R / 2);
  gemm8<256, 0, true><<<384, 512, 0, stream>>>(h1b, wthid, b_hid, nullptr, h2b,
                                               H, H, 128, noise, ns, R / 2, R - R / 2);
  fb_end_kernel<<<B / 4, 256, 0, stream>>>(h2b, W_fb, b_fb, ns, eb, DI, SQDT);
  // bicep: eb @ wtagg^T + b_agg + h2 -> xb (combined), K=256
  gemm8<128, 2, false><<<256, 512, 0, stream>>>(eb, wtagg, b_agg, h2b, xb,
                                                H, P, 256, nullptr, nullptr, 0, 0);
  // final: combined @ W_out^T + b_out -> fp32 d_out, K=1024
  gemm8<128, 3, false><<<256, 512, 0, stream>>>(xb, wtout, b_out, nullptr, d_out,
                                                H, H, 256, nullptr, nullptr, 0, 0);
}

// Round 9
// 189.211 us; speedup vs baseline: 1.9871x; 1.0213x over previous
//
#include <hip/hip_runtime.h>
#include <hip/hip_bf16.h>
#include <math.h>

typedef short bf16x8 __attribute__((ext_vector_type(8)));
typedef float f32x4 __attribute__((ext_vector_type(4)));
typedef unsigned int u32;

#define B_DIM 8192
#define H_DIM 1024
#define NPATH 256
#define NSTEP 50

__device__ __forceinline__ void gld_lds16(const void* g, void* lds) {
  __builtin_amdgcn_global_load_lds(
      (const __attribute__((address_space(1))) u32*)g,
      (__attribute__((address_space(3))) u32*)lds, 16, 0, 0);
}

__device__ __forceinline__ void cast4(const float* in, __hip_bfloat16* out, int i) {
  float4 v = ((const float4*)in)[i];
  union { __hip_bfloat16 h[4]; short4 s; } u;
  u.h[0] = __float2bfloat16(v.x);
  u.h[1] = __float2bfloat16(v.y);
  u.h[2] = __float2bfloat16(v.z);
  u.h[3] = __float2bfloat16(v.w);
  ((short4*)out)[i] = u.s;
}

// ---------------- fused prep: pure data movement ----------------
// [0,8192) cast x ; [8192,11264) transpose W_in/W_hid/W_out ; [11264,11520) W_agg^T
__global__ __launch_bounds__(256) void prep_kernel(
    const float* __restrict__ x, const float* __restrict__ W_in,
    const float* __restrict__ W_hid, const float* __restrict__ W_out,
    const float* __restrict__ W_agg,
    __hip_bfloat16* __restrict__ xb, __hip_bfloat16* __restrict__ wtin,
    __hip_bfloat16* __restrict__ wthid, __hip_bfloat16* __restrict__ wtout,
    __hip_bfloat16* __restrict__ wtagg) {
  __shared__ float t[32][33];
  int bid = blockIdx.x, tid = threadIdx.x;
  if (bid < 8192) {
    cast4(x, xb, bid * 256 + tid);
    return;
  }
  int job = bid - 8192;
  const float* W; __hip_bfloat16* Wt; int R, C;
  if (job < 1024)      { W = W_in;  Wt = wtin;  R = 1024; C = 1024; }
  else if (job < 2048) { W = W_hid; Wt = wthid; R = 1024; C = 1024; job -= 1024; }
  else if (job < 3072) { W = W_out; Wt = wtout; R = 1024; C = 1024; job -= 2048; }
  else                 { W = W_agg; Wt = wtagg; R = 256;  C = 1024; job -= 3072; }
  int nTx = C / 32;
  int tX = job % nTx, tY = job / nTx;
  int tx = tid & 31, r4 = tid >> 5;
#pragma unroll
  for (int i = 0; i < 4; ++i) {
    int ty = r4 * 4 + i;
    t[ty][tx] = W[(size_t)(tY * 32 + ty) * C + tX * 32 + tx];
  }
  __syncthreads();
#pragma unroll
  for (int i = 0; i < 4; ++i) {
    int ty = r4 * 4 + i;
    Wt[(size_t)(tX * 32 + ty) * R + tY * 32 + tx] = __float2bfloat16(t[tx][ty]);
  }
}

// ------------- fused feedback + endpoints: per block = 4 batch rows -------------
__global__ __launch_bounds__(256) void fb_end_kernel(
    const __hip_bfloat16* __restrict__ h2b, const float* __restrict__ Wfb,
    const float* __restrict__ bfb, const float* __restrict__ ns,
    __hip_bfloat16* __restrict__ eb, float DI, float SQDT) {
  __shared__ float fv[4];
  int wid = threadIdx.x >> 6, lane = threadIdx.x & 63;
  int row = blockIdx.x * 4 + wid;
  const __hip_bfloat16* hrow = h2b + (size_t)row * H_DIM;
  float s = 0.f;
#pragma unroll
  for (int i = lane; i < H_DIM; i += 64) s += __bfloat162float(hrow[i]) * Wfb[i];
#pragma unroll
  for (int off = 32; off > 0; off >>= 1) s += __shfl_down(s, off);
  if (lane == 0) fv[wid] = 1.0f / (1.0f + expf(-(s + bfb[0])));
  __syncthreads();
#pragma unroll
  for (int w = 0; w < 4; ++w) {
    size_t i = (size_t)(blockIdx.x * 4 + w) * NPATH + threadIdx.x;
    eb[i] = __float2bfloat16(fv[w] * DI + SQDT * ns[i]);
  }
}

// -------- trunk stage: 128x128-tile GEMM (relu->bf16) + CO-RESIDENT noise ------
// 256 thr, 32KB LDS -> 3-4 blocks/CU: GEMM and noise waves share every CU, so
// noise streams at full-chip HBM BW while GEMM owns the MFMA pipe (m114 overlap).
// odd bid = GEMM tile (bm-major map keeps A-panels L2-warm; B = 2MB L2-resident),
// even bid = noise reduction chunk.
__global__ __launch_bounds__(256) void stage_kernel(
    const __hip_bfloat16* __restrict__ A, const __hip_bfloat16* __restrict__ Bt,
    const float* __restrict__ bias, __hip_bfloat16* __restrict__ out,
    const float* __restrict__ noise, float* __restrict__ ns,
    int rowStart, int rowCount) {
  __shared__ __hip_bfloat16 As[128 * 64];
  __shared__ __hip_bfloat16 Bs[128 * 64];
  const int bid = blockIdx.x;
  if ((bid & 1) == 0) {
    int j = bid >> 1;  // 512 noise blocks, grid-stride
    for (int r = j * 256 + threadIdx.x; r < rowCount; r += 512 * 256) {
      const float2* p = (const float2*)(noise + (size_t)(rowStart + r) * NSTEP);
      float s = 0.f;
#pragma unroll
      for (int i = 0; i < NSTEP / 2; ++i) { float2 v = p[i]; s += v.x + v.y; }
      ns[rowStart + r] = s;
    }
    return;
  }
  const int gb = bid >> 1;                 // 512 tiles: bm-major (A-panel reuse)
  const int bm = gb >> 3, bn = gb & 7;
  const int tid = threadIdx.x;
  const int lane = tid & 63, wid = tid >> 6;
  const int wr = wid >> 1, wc = wid & 1;
  const int frow = lane & 15, kgrp = lane >> 4;

  f32x4 acc[4][4];
#pragma unroll
  for (int m = 0; m < 4; ++m)
#pragma unroll
    for (int n = 0; n < 4; ++n) acc[m][n] = (f32x4){0.f, 0.f, 0.f, 0.f};

  for (int kt = 0; kt < H_DIM; kt += 64) {
#pragma unroll
    for (int r = 0; r < 4; ++r) {
      int c = r * 256 + tid;
      int row = c >> 3, cc = c & 7;
      gld_lds16((const char*)(A + (size_t)(bm * 128 + row) * H_DIM + kt) + cc * 16,
                (char*)As + c * 16);
      gld_lds16((const char*)(Bt + (size_t)(bn * 128 + row) * H_DIM + kt) + cc * 16,
                (char*)Bs + c * 16);
    }
    __syncthreads();
#pragma unroll
    for (int kk = 0; kk < 64; kk += 32) {
      bf16x8 af[4], bfr[4];
#pragma unroll
      for (int m = 0; m < 4; ++m)
        af[m] = *(const bf16x8*)(As + (wr * 64 + m * 16 + frow) * 64 + kk + kgrp * 8);
#pragma unroll
      for (int n = 0; n < 4; ++n)
        bfr[n] = *(const bf16x8*)(Bs + (wc * 64 + n * 16 + frow) * 64 + kk + kgrp * 8);
#pragma unroll
      for (int m = 0; m < 4; ++m)
#pragma unroll
        for (int n = 0; n < 4; ++n)
          acc[m][n] = __builtin_amdgcn_mfma_f32_16x16x32_bf16(af[m], bfr[n], acc[m][n], 0, 0, 0);
    }
    __syncthreads();
  }

  const int r0 = bm * 128 + wr * 64;
  const int c0 = bn * 128 + wc * 64;
#pragma unroll
  for (int n = 0; n < 4; ++n) {
    int col = c0 + n * 16 + frow;
    float bv = bias[col];
#pragma unroll
    for (int m = 0; m < 4; ++m)
#pragma unroll
      for (int j = 0; j < 4; ++j) {
        int row = r0 + m * 16 + kgrp * 4 + j;
        out[(size_t)row * H_DIM + col] = __float2bfloat16(fmaxf(acc[m][n][j] + bv, 0.f));
      }
  }
}

// ---------------- 256-row-tile core for bicep/final (R8 proven) ----------------
// BM=256, BN=128, BK=64, 8 waves, counted-vmcnt dbuf + pre-swizzled-source T2
// + XCD-aware bijective tile remap. MODE 2: +bias+extra->bf16 ; MODE 3: fp32.
template <int MODE>
__global__ __launch_bounds__(512) void gemm8(
    const __hip_bfloat16* __restrict__ A, const __hip_bfloat16* __restrict__ Bt,
    const float* __restrict__ bias, const __hip_bfloat16* __restrict__ extra,
    void* __restrict__ out, int N, int K, int nGemm) {
  constexpr int SMHALF = (256 + 128) * 64 * 2;
  __shared__ char smem[2 * SMHALF];

  const int tid = threadIdx.x;
  const int lane = tid & 63, wid = tid >> 6;
  const int wm = wid >> 2, wn = wid & 3;
  const int frow = lane & 15, kgrp = lane >> 4;
  const int cpx = nGemm >> 3;
  const int gb = (blockIdx.x & 7) * cpx + (blockIdx.x >> 3);  // XCD remap
  const int gx = N / 128;
  const int bm = gb / gx, bn = gb % gx;
  const size_t arow0 = (size_t)(bm * 256) * K;
  const size_t brow0 = (size_t)(bn * 128) * K;

  auto stage = [&](int kt, int d) {
    char* dst = smem + d * SMHALF;
#pragma unroll
    for (int j = 0; j < 6; ++j) {
      int c = j * 512 + tid;
      if (j < 4) {  // A tile: 256x64
        int row = c >> 3, cb = (c & 7) * 16;
        int col = (cb ^ ((row & 7) << 4)) >> 1;
        gld_lds16((const void*)(A + arow0 + (size_t)row * K + kt + col), dst + c * 16);
      } else {      // B tile: 128x64
        int cB = c - 2048;
        int row = cB >> 3, cb = (cB & 7) * 16;
        int col = (cb ^ ((row & 7) << 4)) >> 1;
        gld_lds16((const void*)(Bt + brow0 + (size_t)row * K + kt + col), dst + 32768 + cB * 16);
      }
    }
  };

  f32x4 acc[8][2];
#pragma unroll
  for (int m = 0; m < 8; ++m)
#pragma unroll
    for (int n = 0; n < 2; ++n) acc[m][n] = (f32x4){0.f, 0.f, 0.f, 0.f};

  stage(0, 0);
  const int NT = K >> 6;
  for (int t = 0; t < NT; ++t) {
    const int cur = t & 1;
    if (t + 1 < NT) stage((t + 1) << 6, cur ^ 1);
    if (t == 0 || t + 1 >= NT) {
      asm volatile("s_waitcnt vmcnt(0)" ::: "memory");
    } else {
      asm volatile("s_waitcnt vmcnt(6)" ::: "memory");
    }
    __builtin_amdgcn_s_barrier();

    const char* Ab = smem + cur * SMHALF;
    const char* Bb = Ab + 32768;
    bf16x8 bfr[2][2];
#pragma unroll
    for (int n = 0; n < 2; ++n)
#pragma unroll
      for (int s = 0; s < 2; ++s) {
        int row = wn * 32 + n * 16 + frow;
        int cb = s * 64 + kgrp * 16;
        bfr[n][s] = *(const bf16x8*)(Bb + row * 128 + (cb ^ ((row & 7) << 4)));
      }
#pragma unroll
    for (int mh = 0; mh < 2; ++mh) {
      bf16x8 af[4][2];
#pragma unroll
      for (int m = 0; m < 4; ++m)
#pragma unroll
        for (int s = 0; s < 2; ++s) {
          int row = wm * 128 + (mh * 4 + m) * 16 + frow;
          int cb = s * 64 + kgrp * 16;
          af[m][s] = *(const bf16x8*)(Ab + row * 128 + (cb ^ ((row & 7) << 4)));
        }
#pragma unroll
      for (int m = 0; m < 4; ++m)
#pragma unroll
        for (int n = 0; n < 2; ++n)
#pragma unroll
          for (int s = 0; s < 2; ++s)
            acc[mh * 4 + m][n] = __builtin_amdgcn_mfma_f32_16x16x32_bf16(
                af[m][s], bfr[n][s], acc[mh * 4 + m][n], 0, 0, 0);
    }
    __builtin_amdgcn_s_barrier();
  }

  const int r0 = bm * 256 + wm * 128;
  const int c0 = bn * 128 + wn * 32;
#pragma unroll
  for (int n = 0; n < 2; ++n) {
    int col = c0 + n * 16 + frow;
    float bv = bias[col];
#pragma unroll
    for (int m = 0; m < 8; ++m)
#pragma unroll
      for (int j = 0; j < 4; ++j) {
        int row = r0 + m * 16 + kgrp * 4 + j;
        float v = acc[m][n][j] + bv;
        if (MODE == 2) {
          v += __bfloat162float(extra[(size_t)row * N + col]);
          ((__hip_bfloat16*)out)[(size_t)row * N + col] = __float2bfloat16(v);
        } else {
          ((float*)out)[(size_t)row * N + col] = v;
        }
      }
  }
}

extern "C" void kernel_launch(void* const* d_in, const int* in_sizes, int n_in,
                              void* d_out, int out_size, void* d_ws, size_t ws_size,
                              hipStream_t stream) {
  (void)in_sizes; (void)n_in; (void)out_size; (void)ws_size;
  const float* x     = (const float*)d_in[0];
  const float* W_in  = (const float*)d_in[1];
  const float* b_in  = (const float*)d_in[2];
  const float* W_hid = (const float*)d_in[3];
  const float* b_hid = (const float*)d_in[4];
  const float* W_fb  = (const float*)d_in[5];
  const float* b_fb  = (const float*)d_in[6];
  const float* W_agg = (const float*)d_in[7];
  const float* b_agg = (const float*)d_in[8];
  const float* W_out = (const float*)d_in[9];
  const float* b_out = (const float*)d_in[10];
  const float* noise = (const float*)d_in[11];

  const int B = B_DIM, H = H_DIM, P = NPATH;
  const int R = B * P;

  size_t off = 0;
  char* base = (char*)d_ws;
  auto take = [&](size_t bytes) -> char* {
    char* r = base + off;
    off = (off + bytes + 255) & ~(size_t)255;
    return r;
  };
  __hip_bfloat16* xb    = (__hip_bfloat16*)take((size_t)B * H * 2);  // reused as `combined`
  __hip_bfloat16* h1b   = (__hip_bfloat16*)take((size_t)B * H * 2);
  __hip_bfloat16* h2b   = (__hip_bfloat16*)take((size_t)B * H * 2);
  __hip_bfloat16* wtin  = (__hip_bfloat16*)take((size_t)H * H * 2);
  __hip_bfloat16* wthid = (__hip_bfloat16*)take((size_t)H * H * 2);
  __hip_bfloat16* wtout = (__hip_bfloat16*)take((size_t)H * H * 2);
  __hip_bfloat16* wtagg = (__hip_bfloat16*)take((size_t)H * P * 2);
  float* ns = (float*)take((size_t)R * 4);
  __hip_bfloat16* eb = (__hip_bfloat16*)take((size_t)R * 2);

  float dt = 1.0f / NSTEP;
  float DI = 0.f;
  for (int j = 0; j < NSTEP; ++j) DI += expf(-0.1f * ((float)j * dt));
  DI *= dt;
  float SQDT = sqrtf(dt);

  prep_kernel<<<11520, 256, 0, stream>>>(x, W_in, W_hid, W_out, W_agg,
                                         xb, wtin, wthid, wtout, wtagg);

  // trunk stages: 512 GEMM tiles + 512 noise blocks, co-resident (32KB LDS)
  stage_kernel<<<1024, 256, 0, stream>>>(xb, wtin, b_in, h1b, noise, ns, 0, R / 2);
  stage_kernel<<<1024, 256, 0, stream>>>(h1b, wthid, b_hid, h2b, noise, ns, R / 2, R - R / 2);
  fb_end_kernel<<<B / 4, 256, 0, stream>>>(h2b, W_fb, b_fb, ns, eb, DI, SQDT);
  // bicep: eb @ wtagg^T + b_agg + h2 -> xb (combined), K=256
  gemm8<2><<<256, 512, 0, stream>>>(eb, wtagg, b_agg, h2b, xb, H, P, 256);
  // final: combined @ W_out^T + b_out -> fp32 d_out, K=1024
  gemm8<3><<<256, 512, 0, stream>>>(xb, wtout, b_out, nullptr, d_out, H, H, 256);
}